// Round 7
// baseline (268.098 us; speedup 1.0000x reference)
//
#include <hip/hip_runtime.h>
#include <math.h>

#define BB 16
#define H 1024
#define W 1024
#define HW (H*W)
#define NTOT (BB*HW)

typedef unsigned long long u64;

// float32 of np.exp(-0.5*(n/1)^2), n=-2..2 (correctly-rounded decimal literals)
__device__ __constant__ float GW[5] = {
    0.13533528323661270f, 0.60653065971263342f, 1.0f,
    0.60653065971263342f, 0.13533528323661270f};

// NMS neighbor offsets per direction bucket
// 0:E 1:SE 2:S 3:SW 4:W 5:NW 6:N 7:NE
__device__ __constant__ int NBDY[8] = {0, 1, 1, 1, 0, -1, -1, -1};
__device__ __constant__ int NBDX[8] = {1, 1, 0, -1, -1, -1, 0, 1};

#define CSCALE ((float)(180.0 / 3.1415926))

// Cephes atanf core: input in [0,1], error ~1e-7 rad
__device__ __forceinline__ float atan_poly01(float xin) {
    float y0 = 0.0f, x = xin;
    if (xin > 0.41421356f) {
        x = __fdividef(xin - 1.0f, xin + 1.0f);
        y0 = 0.78539816339f;  // pi/4
    }
    float z = x * x;
    float p = ((8.05374449538e-2f * z - 1.38776856032e-1f) * z + 1.99777106478e-1f) * z
              - 3.33329491539e-1f;
    return y0 + (p * z * x + x);
}

// =====================================================================
// K1: fused gaussian(h)+gaussian(v)+sobel+mag+bucket + per-block magmax
// Tile 128x16. Stage C zeroes the sm halo at image borders so stage D
// runs UNGUARDED; all LDS access float4-vectorized (conflict-free).
// =====================================================================
#define TW 128
#define TH 16
// sA: img rows y0-3..y0+18 (22), cols x0-4..x0+131 (136 w), stride 136 (+slack)
// sB: gh  rows 22, cols x0-1+c (132 w incl 2 garbage), stride 132
// sm overlays sA: rows 18 <-> y0-1..y0+16, col c <-> x0-1+c (zeroed if OOB)
__global__ __launch_bounds__(256, 6) void k_smooth_sobel(const float* __restrict__ img,
                                                         float* __restrict__ mag,
                                                         unsigned char* __restrict__ bucket,
                                                         float* __restrict__ partial) {
#pragma clang fp contract(off)
    __shared__ float sA[22 * 136 + 16];
    __shared__ float sB[22 * 132];
    __shared__ float red[256];

    const int tid = threadIdx.x;
    const int x0 = blockIdx.x * TW;
    const int y0 = blockIdx.y * TH;
    const int b = blockIdx.z;
    const size_t base = (size_t)b * HW;

    // ---- stage A: load img tile + halo (float4, all-or-nothing per vec) ----
    for (int idx = tid; idx < 22 * 34; idx += 256) {
        int r = idx / 34, v = idx - r * 34;
        int gy = y0 - 3 + r;
        int gxv = x0 - 4 + v * 4;
        float4 val = make_float4(0.f, 0.f, 0.f, 0.f);
        if (gy >= 0 && gy < H && gxv >= 0 && gxv <= W - 4)
            val = *(const float4*)&img[base + (size_t)gy * W + gxv];
        *(float4*)&sA[r * 136 + v * 4] = val;
    }
    __syncthreads();

    // ---- stage B: horizontal gaussian, 4 cols/iter ----
    // sB col c <-> global x0-1+c ; taps = sA cols c+1..c+5
    for (int idx = tid; idx < 22 * 33; idx += 256) {
        int r = idx / 33, g = idx - r * 33;
        const float* p = &sA[r * 136 + g * 4];
        float4 A0 = *(const float4*)p;
        float4 A1 = *(const float4*)(p + 4);
        float4 A2 = *(const float4*)(p + 8);
        float a_[12] = {A0.x, A0.y, A0.z, A0.w, A1.x, A1.y, A1.z, A1.w,
                        A2.x, A2.y, A2.z, A2.w};
        float o[4];
#pragma unroll
        for (int j = 0; j < 4; ++j) {
            float s = 0.0f;
#pragma unroll
            for (int k = 0; k < 5; ++k) s = s + GW[k] * a_[j + 1 + k];
            o[j] = s;
        }
        *(float4*)&sB[r * 132 + g * 4] = make_float4(o[0], o[1], o[2], o[3]);
    }
    __syncthreads();

    // ---- stage C: vertical gaussian -> sm (overlays sA), ZERO at image OOB ----
    for (int idx = tid; idx < 18 * 33; idx += 256) {
        int rr = idx / 33, g = idx - rr * 33;
        float bb[20];
#pragma unroll
        for (int k = 0; k < 5; ++k) {
            float4 t = *(const float4*)&sB[(rr + k) * 132 + g * 4];
            bb[k * 4 + 0] = t.x; bb[k * 4 + 1] = t.y;
            bb[k * 4 + 2] = t.z; bb[k * 4 + 3] = t.w;
        }
        int gy = y0 - 1 + rr;
        bool rowok = (gy >= 0 && gy < H);
        float o[4];
#pragma unroll
        for (int j = 0; j < 4; ++j) {
            float s = 0.0f;
#pragma unroll
            for (int k = 0; k < 5; ++k) s = s + GW[k] * bb[k * 4 + j];
            int gx = x0 - 1 + g * 4 + j;
            o[j] = (rowok && gx >= 0 && gx < W) ? s : 0.0f;
        }
        *(float4*)&sA[rr * 136 + g * 4] = make_float4(o[0], o[1], o[2], o[3]);
    }
    __syncthreads();

    // ---- stage D: sobel + mag + bucket, unguarded vector LDS reads ----
    // pixel (y0+r, x0+c): sm(y+dy,x+dx) = sA[(r+1+dy)*136 + (c+1+dx)]
    float tmax = 0.0f;
#pragma unroll
    for (int k2 = 0; k2 < 2; ++k2) {
        int v = tid + k2 * 256;          // 0..511
        int r = v >> 5;                  // 0..15
        int cg = (v & 31) * 4;           // 0..124
        int y = y0 + r;
        const float* P0 = &sA[r * 136 + cg];
        const float* P1 = P0 + 136;
        const float* P2 = P1 + 136;
        float4 q0 = *(const float4*)P0; float2 e0 = *(const float2*)(P0 + 4);
        float4 q1 = *(const float4*)P1; float2 e1 = *(const float2*)(P1 + 4);
        float4 q2 = *(const float4*)P2; float2 e2 = *(const float2*)(P2 + 4);
        float r0[6] = {q0.x, q0.y, q0.z, q0.w, e0.x, e0.y};
        float r1[6] = {q1.x, q1.y, q1.z, q1.w, e1.x, e1.y};
        float r2[6] = {q2.x, q2.y, q2.z, q2.w, e2.x, e2.y};

        float mg[4];
        unsigned int bk = 0;
#pragma unroll
        for (int j = 0; j < 4; ++j) {
            float a00 = r0[j], a01 = r0[j + 1], a02 = r0[j + 2];
            float a10 = r1[j],                  a12 = r1[j + 2];
            float a20 = r2[j], a21 = r2[j + 1], a22 = r2[j + 2];

            float Ix = a00;
            Ix = Ix - a02;
            Ix = Ix + 2.0f * a10;
            Ix = Ix - 2.0f * a12;
            Ix = Ix + a20;
            Ix = Ix - a22;

            float Iy = a00;
            Iy = Iy + 2.0f * a01;
            Iy = Iy + a02;
            Iy = Iy - a20;
            Iy = Iy - 2.0f * a21;
            Iy = Iy - a22;

            float t1 = Ix * Ix;
            float t2 = Iy * Iy;
            float m = sqrtf(t1 + t2);
            mg[j] = m;
            tmax = fmaxf(tmax, m);

            // fast octant classification; exact double fallback near boundaries
            float ax = fabsf(Ix), ay = fabsf(Iy);
            float mn = fminf(ax, ay), mx = fmaxf(ax, ay);
            float zr = __fdividef(mn, mx);
            float bse = atan_poly01(zr);
            float phi = (ay > ax) ? (1.57079632679f - bse) : bse;
            if (Ix < 0.0f) phi = 3.14159265359f - phi;
            float theta = (Iy >= 0.0f) ? phi : -phi;
            float t = (theta * CSCALE + 180.0f) * (1.0f / 45.0f);
            float rr2 = rintf(t);
            if ((mx < 1e-30f) || (0.5f - fabsf(t - rr2) < 1e-4f)) {
                float fa2 = (float)atan2((double)Iy, (double)Ix);
                float d2 = fa2 * CSCALE;
                d2 = d2 + 180.0f;
                float t2d = d2 / 45.0f;
                rr2 = rintf(t2d);
            }
            int bidx = ((int)rr2) & 7;   // values 0..8 -> 8 wraps to 0
            bk |= ((unsigned int)bidx) << (8 * j);
        }
        *(float4*)&mag[base + (size_t)y * W + x0 + cg] = make_float4(mg[0], mg[1], mg[2], mg[3]);
        *(unsigned int*)&bucket[base + (size_t)y * W + x0 + cg] = bk;
    }

    red[tid] = tmax;
    __syncthreads();
    for (int s = 128; s > 0; s >>= 1) {
        if (tid < s) red[tid] = fmaxf(red[tid], red[tid + s]);
        __syncthreads();
    }
    if (tid == 0) {
        int pb = (blockIdx.z * 64 + blockIdx.y) * 8 + blockIdx.x;  // 512 per image
        partial[pb] = red[0];
    }
}

// ---------------- per-image max over 512 block partials ----------------
__global__ __launch_bounds__(256) void k_redmax_img(const float* __restrict__ partial,
                                                    float* __restrict__ magmax) {
    __shared__ float red[256];
    const float* p = partial + blockIdx.x * 512;
    float m = fmaxf(p[threadIdx.x], p[threadIdx.x + 256]);
    red[threadIdx.x] = m;
    __syncthreads();
    for (int s = 128; s > 0; s >>= 1) {
        if (threadIdx.x < s) red[threadIdx.x] = fmaxf(red[threadIdx.x], red[threadIdx.x + s]);
        __syncthreads();
    }
    if (threadIdx.x == 0) magmax[blockIdx.x] = red[0];
}

// ---------------- global max over 4096 nms-block partials ----------------
__global__ __launch_bounds__(1024) void k_redmax_all(const float* __restrict__ partial,
                                                     float* __restrict__ thinmax) {
    __shared__ float red[1024];
    float m = 0.0f;
    for (int k = threadIdx.x; k < 4096; k += 1024) m = fmaxf(m, partial[k]);
    red[threadIdx.x] = m;
    __syncthreads();
    for (int s = 512; s > 0; s >>= 1) {
        if (threadIdx.x < s) red[threadIdx.x] = fmaxf(red[threadIdx.x], red[threadIdx.x + s]);
        __syncthreads();
    }
    if (threadIdx.x == 0) *thinmax = red[0];
}

// =====================================================================
// NMS: division-free compares on RAW mag in LDS; emits is_max bitmask
// (tile-major, same layout as Sb/Wb) + per-block max of thin.
// Exactness: a<=b  => RN(a/M)<=RN(b/M) (monotone) => not strictly greater.
//            a>=b*1.0000005f => real quotient gap > 3.9 ulp => RN differ.
//            in-between band (P~1e-6): exact IEEE divides, wave-uniform branch.
// sN col j <-> x0-4+j ; row r' <-> y0-1+r'.
// =====================================================================
__global__ __launch_bounds__(256, 8) void k_nms_b(const float* __restrict__ mag,
                                                  const unsigned char* __restrict__ bucket,
                                                  const float* __restrict__ magmax,
                                                  u64* __restrict__ Mb,
                                                  float* __restrict__ partial) {
#pragma clang fp contract(off)
    __shared__ float sN[34 * 136];
    __shared__ float red[256];

    const int tid = threadIdx.x;
    const int x0 = blockIdx.x * 128;
    const int y0 = blockIdx.y * 32;
    const int b = blockIdx.z;
    const size_t base = (size_t)b * HW;
    const float M = magmax[b];

    for (int idx = tid; idx < 34 * 34; idx += 256) {
        int r = idx / 34, v = idx - r * 34;
        int gy = y0 - 1 + r;
        int gxv = x0 - 4 + v * 4;
        float4 val = make_float4(0.f, 0.f, 0.f, 0.f);
        if (gy >= 0 && gy < H && gxv >= 0 && gxv <= W - 4)
            val = *(const float4*)&mag[base + (size_t)gy * W + gxv];
        *(float4*)&sN[r * 136 + v * 4] = val;
    }
    __syncthreads();

    const int wv = tid >> 6, L = tid & 63;
    const int h = wv & 1, wr = wv >> 1;
    const int txw = (x0 >> 6) + h;
    float amax = 0.0f;

#pragma unroll
    for (int i = 0; i < 16; ++i) {
        int r = i * 2 + wr;          // 0..31
        int c = h * 64 + L;          // 0..127
        int y = y0 + r;
        unsigned int bkt = bucket[base + (size_t)y * W + x0 + c];
        int dy = NBDY[bkt], dx = NBDX[bkt];
        float a  = sN[(r + 1) * 136 + c + 4];
        float bp = sN[(r + 1 + dy) * 136 + c + 4 + dx];
        float bn = sN[(r + 1 - dy) * 136 + c + 4 - dx];
        bool g1 = a > bp, g2 = a > bn;
        bool f1 = a >= bp * 1.0000005f;
        bool f2 = a >= bn * 1.0000005f;
        bool r1 = g1, r2 = g2;
        if (__any((g1 && !f1) || (g2 && !f2))) {
            float qa = a / M;
            if (g1 && !f1) r1 = qa > (bp / M);
            if (g2 && !f2) r2 = qa > (bn / M);
        }
        bool im = r1 && r2;
        if (im) amax = fmaxf(amax, a);
        u64 word = __ballot(im);
        if (L == 0) {
            int ty = y >> 6, row = y & 63;
            Mb[((b << 8) | (ty << 4) | txw) * 64 + row] = word;
        }
    }

    red[tid] = amax;
    __syncthreads();
    for (int s = 128; s > 0; s >>= 1) {
        if (tid < s) red[tid] = fmaxf(red[tid], red[tid + s]);
        __syncthreads();
    }
    // max(thin) over block = RN(max_surviving_a / M): RN monotone => exact
    if (tid == 0)
        partial[(blockIdx.z * 32 + blockIdx.y) * 8 + blockIdx.x] = red[0] / M;
}

// ---------------- per-image threshold bisection ----------------
// thr[2b] = min{a : RN(a/M_b) >= LOW_T}, thr[2b+1] = min{a : RN(a/M_b) >= hi}
__global__ void k_bisect(const float* __restrict__ hdr, float* __restrict__ thr) {
    int t = threadIdx.x;
    if (t >= 32) return;
    int b = t >> 1;
    float M = hdr[b];
    float T = (t & 1) ? (hdr[16] * 0.15f) : 0.00392f;
    if (0.0f / M >= T) { thr[t] = 0.0f; return; }
    unsigned int lo = 0u, hi = 0x7f800000u;  // P(inf)=true bracket
    while (hi - lo > 1u) {
        unsigned int mid = lo + ((hi - lo) >> 1);
        if (__uint_as_float(mid) / M >= T) hi = mid; else lo = mid;
    }
    thr[t] = __uint_as_float(hi);
}

// ---------------- threshold: mag + is_max bits -> Sb/Wb (no division) ----------------
__global__ __launch_bounds__(256) void k_thresh_b(const float* __restrict__ mag,
                                                  const u64* __restrict__ Mb,
                                                  const float* __restrict__ hdr,
                                                  const float* __restrict__ thr,
                                                  u64* __restrict__ Sb,
                                                  u64* __restrict__ Wb) {
    const int tid = threadIdx.x;
    const int x0 = blockIdx.x * 128;
    const int y0 = blockIdx.y * 32;
    const int b = blockIdx.z;
    const size_t base = (size_t)b * HW;
    const float Alo = thr[b * 2], Ahi = thr[b * 2 + 1];
    const bool snm = (hdr[16] * 0.15f <= 0.0f);  // degenerate: thin=0 also "strong"
    const int wv = tid >> 6, L = tid & 63;
    const int h = wv & 1, wr = wv >> 1;
    const int txw = (x0 >> 6) + h;

#pragma unroll
    for (int i = 0; i < 16; ++i) {
        int r = i * 2 + wr;
        int y = y0 + r;
        float a = mag[base + (size_t)y * W + x0 + h * 64 + L];
        int ty = y >> 6, row = y & 63;
        int widx = ((b << 8) | (ty << 4) | txw) * 64 + row;
        bool im = (Mb[widx] >> L) & 1ull;
        bool strong = snm || (im && (a >= Ahi));
        bool weak = (!strong) && im && (a >= Alo);
        u64 sw = __ballot(strong);
        u64 ww = __ballot(weak);
        if (L == 0) { Sb[widx] = sw; Wb[widx] = ww; }
    }
}

// ---------------- hysteresis: bit-parallel 64x64 tile per wave, tile-major ----------------
__global__ __launch_bounds__(256) void k_hyster_bits(const u64* __restrict__ Wb,
                                                     u64* __restrict__ Sb) {
    const int lane = threadIdx.x & 63;
    const int t = blockIdx.x * 4 + (threadIdx.x >> 6);  // global tile id = b*256+ty*16+tx
    const int ty = (t >> 4) & 15;
    const int tx = t & 15;
    const int idx = t * 64 + lane;

    u64 S = Sb[idx];
    const u64 Wk = Wb[idx];

    u64 hstat = 0;
    if (tx > 0)  hstat |= (Sb[(t - 1) * 64 + lane] >> 63) & 1ull;
    if (tx < 15) hstat |= (Sb[(t + 1) * 64 + lane] & 1ull) << 63;

    u64 halo = 0;
    if (lane == 0 && ty > 0) {
        const int ta = t - 16;
        u64 tc = Sb[ta * 64 + 63];
        u64 hh = (tc << 1) | tc | (tc >> 1);
        if (tx > 0)  hh |= (Sb[(ta - 1) * 64 + 63] >> 63) & 1ull;
        if (tx < 15) hh |= (Sb[(ta + 1) * 64 + 63] & 1ull) << 63;
        halo = hh;
    }
    if (lane == 63 && ty < 15) {
        const int tb = t + 16;
        u64 tc = Sb[tb * 64 + 0];
        u64 hh = (tc << 1) | tc | (tc >> 1);
        if (tx > 0)  hh |= (Sb[(tb - 1) * 64 + 0] >> 63) & 1ull;
        if (tx < 15) hh |= (Sb[(tb + 1) * 64 + 0] & 1ull) << 63;
        halo = hh;
    }

    for (int it = 0; it < 160; ++it) {
        u64 hh = (S << 1) | S | (S >> 1) | hstat;
        u64 up = __shfl_up(hh, 1, 64);
        if (lane == 0) up = halo;
        u64 dn = __shfl_down(hh, 1, 64);
        if (lane == 63) dn = halo;
        u64 dil = hh | up | dn;
        u64 nS = S | (Wk & dil);
        bool ch = (nS != S);
        S = nS;
        if (!__any(ch)) break;
    }

    Sb[idx] = S;
}

// ---------------- finalize: strong bit -> 255 else 0, float4 stores ----------------
__global__ __launch_bounds__(256) void k_final4(const u64* __restrict__ Sb,
                                                float* __restrict__ out) {
    const int gid = blockIdx.x * 256 + threadIdx.x;
    const int p0 = gid * 4;
    const int x = p0 & (W - 1);
    const int y = (p0 >> 10) & (H - 1);
    const int b = p0 >> 20;
    const int widx = ((b << 8) | ((y >> 6) << 4) | (x >> 6)) * 64 + (y & 63);
    const u64 w = Sb[widx];
    const unsigned int nib = (unsigned int)((w >> (x & 63)) & 0xFull);
    float4 o;
    o.x = (nib & 1u) ? 255.0f : 0.0f;
    o.y = (nib & 2u) ? 255.0f : 0.0f;
    o.z = (nib & 4u) ? 255.0f : 0.0f;
    o.w = (nib & 8u) ? 255.0f : 0.0f;
    *(float4*)&out[p0] = o;
}

extern "C" void kernel_launch(void* const* d_in, const int* in_sizes, int n_in,
                              void* d_out, int out_size, void* d_ws, size_t ws_size,
                              hipStream_t stream) {
    (void)in_sizes; (void)n_in; (void)out_size; (void)ws_size;
    const float* img = (const float*)d_in[0];
    float* out = (float*)d_out;

    // workspace layout
    float* hdr = (float*)d_ws;                 // [0..15]=magmax, [16]=thinmax
    float* thr = hdr + 64;                     // 32 floats: per-image Alo/Ahi
    float* partialA = hdr + 128;               // 8192 floats (K1 blocks)
    float* partialB = partialA + 8192;         // 4096 floats (nms blocks)
    float* A = partialB + 4096;                // mag, 64 MB (16B-aligned)
    unsigned char* C = (unsigned char*)(A + (size_t)NTOT);  // bucket, 16 MB
    u64* Sb = (u64*)(C + (size_t)NTOT);        // strong bits, 2 MB
    u64* Wb = Sb + NTOT / 64;                  // weak bits, 2 MB
    u64* Mb = Wb + NTOT / 64;                  // is_max bits, 2 MB

    dim3 blk(256);
    k_smooth_sobel<<<dim3(8, 64, BB), blk, 0, stream>>>(img, A, C, partialA);
    k_redmax_img<<<dim3(BB), blk, 0, stream>>>(partialA, hdr);
    k_nms_b<<<dim3(8, 32, BB), blk, 0, stream>>>(A, C, hdr, Mb, partialB);
    k_redmax_all<<<dim3(1), dim3(1024), 0, stream>>>(partialB, hdr + 16);
    k_bisect<<<dim3(1), dim3(64), 0, stream>>>(hdr, thr);
    k_thresh_b<<<dim3(8, 32, BB), blk, 0, stream>>>(A, Mb, hdr, thr, Sb, Wb);
    for (int p = 0; p < 6; ++p)
        k_hyster_bits<<<dim3(NTOT / (64 * 64) / 4), blk, 0, stream>>>(Wb, Sb);
    k_final4<<<dim3(NTOT / 1024), blk, 0, stream>>>(Sb, out);
}

// Round 8
// 242.622 us; speedup vs baseline: 1.1050x; 1.1050x over previous
//
#include <hip/hip_runtime.h>
#include <math.h>

#define BB 16
#define H 1024
#define W 1024
#define HW (H*W)
#define NTOT (BB*HW)

typedef unsigned long long u64;

// float32 of np.exp(-0.5*(n/1)^2), n=-2..2 (correctly-rounded decimal literals)
__device__ __constant__ float GW[5] = {
    0.13533528323661270f, 0.60653065971263342f, 1.0f,
    0.60653065971263342f, 0.13533528323661270f};

// NMS neighbor offsets per direction bucket
// 0:E 1:SE 2:S 3:SW 4:W 5:NW 6:N 7:NE
__device__ __constant__ int NBDY[8] = {0, 1, 1, 1, 0, -1, -1, -1};
__device__ __constant__ int NBDX[8] = {1, 1, 0, -1, -1, -1, 0, 1};

#define CSCALE ((float)(180.0 / 3.1415926))

// =====================================================================
// K1: fused gaussian(h)+gaussian(v)+sobel+mag+bucket + per-block magmax
// Tile 128x8. LDS ~16.2 KB -> 8 blocks/CU (wave cap). Bucket by pure
// comparisons (exact outside a conservative boundary band; band falls
// back to the proven exact double-atan2 chain).
// =====================================================================
#define TW 128
#define TH 8
// sA: img rows y0-3..y0+10 (14), cols x0-4..x0+131 (136 w), stride 136 (+slack)
// sB: gh  rows 14, stride 132 (cols 130/131 garbage-fed but never consumed)
// sm overlays sA: rows 10 <-> y0-1..y0+8, col c <-> x0-1+c (zeroed if OOB)
__global__ __launch_bounds__(256, 8) void k_smooth_sobel(const float* __restrict__ img,
                                                         float* __restrict__ mag,
                                                         unsigned char* __restrict__ bucket,
                                                         float* __restrict__ partial) {
#pragma clang fp contract(off)
    __shared__ float sA[14 * 136 + 16];
    __shared__ float sB[14 * 132];
    __shared__ float red[256];

    const int tid = threadIdx.x;
    const int x0 = blockIdx.x * TW;
    const int y0 = blockIdx.y * TH;
    const int b = blockIdx.z;
    const size_t base = (size_t)b * HW;

    // ---- stage A: load img tile + halo (float4, all-or-nothing per vec) ----
    for (int idx = tid; idx < 14 * 34; idx += 256) {
        int r = idx / 34, v = idx - r * 34;
        int gy = y0 - 3 + r;
        int gxv = x0 - 4 + v * 4;
        float4 val = make_float4(0.f, 0.f, 0.f, 0.f);
        if (gy >= 0 && gy < H && gxv >= 0 && gxv <= W - 4)
            val = *(const float4*)&img[base + (size_t)gy * W + gxv];
        *(float4*)&sA[r * 136 + v * 4] = val;
    }
    __syncthreads();

    // ---- stage B: horizontal gaussian, 4 cols/iter ----
    for (int idx = tid; idx < 14 * 33; idx += 256) {
        int r = idx / 33, g = idx - r * 33;
        const float* p = &sA[r * 136 + g * 4];
        float4 A0 = *(const float4*)p;
        float4 A1 = *(const float4*)(p + 4);
        float4 A2 = *(const float4*)(p + 8);
        float a_[12] = {A0.x, A0.y, A0.z, A0.w, A1.x, A1.y, A1.z, A1.w,
                        A2.x, A2.y, A2.z, A2.w};
        float o[4];
#pragma unroll
        for (int j = 0; j < 4; ++j) {
            float s = 0.0f;
#pragma unroll
            for (int k = 0; k < 5; ++k) s = s + GW[k] * a_[j + 1 + k];
            o[j] = s;
        }
        *(float4*)&sB[r * 132 + g * 4] = make_float4(o[0], o[1], o[2], o[3]);
    }
    __syncthreads();

    // ---- stage C: vertical gaussian -> sm (overlays sA), ZERO at image OOB ----
    for (int idx = tid; idx < 10 * 33; idx += 256) {
        int rr = idx / 33, g = idx - rr * 33;
        float bb[20];
#pragma unroll
        for (int k = 0; k < 5; ++k) {
            float4 t = *(const float4*)&sB[(rr + k) * 132 + g * 4];
            bb[k * 4 + 0] = t.x; bb[k * 4 + 1] = t.y;
            bb[k * 4 + 2] = t.z; bb[k * 4 + 3] = t.w;
        }
        int gy = y0 - 1 + rr;
        bool rowok = (gy >= 0 && gy < H);
        float o[4];
#pragma unroll
        for (int j = 0; j < 4; ++j) {
            float s = 0.0f;
#pragma unroll
            for (int k = 0; k < 5; ++k) s = s + GW[k] * bb[k * 4 + j];
            int gx = x0 - 1 + g * 4 + j;
            o[j] = (rowok && gx >= 0 && gx < W) ? s : 0.0f;
        }
        *(float4*)&sA[rr * 136 + g * 4] = make_float4(o[0], o[1], o[2], o[3]);
    }
    __syncthreads();

    // ---- stage D: sobel + mag + bucket (comparisons), 4 px/thread ----
    const int r = tid >> 5;            // 0..7
    const int cg = (tid & 31) * 4;     // 0..124
    const int y = y0 + r;
    const float* P0 = &sA[r * 136 + cg];
    const float* P1 = P0 + 136;
    const float* P2 = P1 + 136;
    float4 q0 = *(const float4*)P0; float2 e0 = *(const float2*)(P0 + 4);
    float4 q1 = *(const float4*)P1; float2 e1 = *(const float2*)(P1 + 4);
    float4 q2 = *(const float4*)P2; float2 e2 = *(const float2*)(P2 + 4);
    float r0[6] = {q0.x, q0.y, q0.z, q0.w, e0.x, e0.y};
    float r1[6] = {q1.x, q1.y, q1.z, q1.w, e1.x, e1.y};
    float r2[6] = {q2.x, q2.y, q2.z, q2.w, e2.x, e2.y};

    float tmax = 0.0f;
    float mg[4];
    unsigned int bk = 0;
#pragma unroll
    for (int j = 0; j < 4; ++j) {
        float a00 = r0[j], a01 = r0[j + 1], a02 = r0[j + 2];
        float a10 = r1[j],                  a12 = r1[j + 2];
        float a20 = r2[j], a21 = r2[j + 1], a22 = r2[j + 2];

        float Ix = a00;
        Ix = Ix - a02;
        Ix = Ix + 2.0f * a10;
        Ix = Ix - 2.0f * a12;
        Ix = Ix + a20;
        Ix = Ix - a22;

        float Iy = a00;
        Iy = Iy + 2.0f * a01;
        Iy = Iy + a02;
        Iy = Iy - a20;
        Iy = Iy - 2.0f * a21;
        Iy = Iy - a22;

        float t1 = Ix * Ix;
        float t2 = Iy * Iy;
        float m = sqrtf(t1 + t2);
        mg[j] = m;
        tmax = fmaxf(tmax, m);

        // octant by comparisons; conservative band -> exact double fallback
        float ax = fabsf(Ix), ay = fabsf(Iy);
        float mn = fminf(ax, ay), mx = fmaxf(ax, ay);
        float cr = mn * 0.92387953f - mx * 0.38268343f;  // r*sin(alpha-22.5deg)
        int bidx;
        if (fabsf(cr) < mx * 3e-5f) {
            float fa2 = (float)atan2((double)Iy, (double)Ix);
            float d2 = fa2 * CSCALE;
            d2 = d2 + 180.0f;
            float t2d = d2 / 45.0f;
            float rr2 = rintf(t2d);
            bidx = ((int)rr2) & 7;
        } else if (ay <= ax * 0.41421356f) {          // near-horizontal
            bidx = signbit(Ix) ? 0 : 4;
        } else if (ay >= ax * 2.41421356f) {          // near-vertical
            bidx = (Iy >= 0.0f) ? 6 : 2;
        } else {                                      // diagonal
            bidx = (Iy >= 0.0f) ? ((Ix >= 0.0f) ? 5 : 7)
                                : ((Ix >= 0.0f) ? 3 : 1);
        }
        bk |= ((unsigned int)bidx) << (8 * j);
    }
    *(float4*)&mag[base + (size_t)y * W + x0 + cg] = make_float4(mg[0], mg[1], mg[2], mg[3]);
    *(unsigned int*)&bucket[base + (size_t)y * W + x0 + cg] = bk;

    red[tid] = tmax;
    __syncthreads();
    for (int s = 128; s > 0; s >>= 1) {
        if (tid < s) red[tid] = fmaxf(red[tid], red[tid + s]);
        __syncthreads();
    }
    if (tid == 0) {
        int pb = (blockIdx.z * 128 + blockIdx.y) * 8 + blockIdx.x;  // 1024 per image
        partial[pb] = red[0];
    }
}

// ---------------- per-image max over 1024 block partials ----------------
__global__ __launch_bounds__(256) void k_redmax_img(const float* __restrict__ partial,
                                                    float* __restrict__ magmax) {
    __shared__ float red[256];
    const float* p = partial + blockIdx.x * 1024;
    float m = 0.0f;
    for (int k = threadIdx.x; k < 1024; k += 256) m = fmaxf(m, p[k]);
    red[threadIdx.x] = m;
    __syncthreads();
    for (int s = 128; s > 0; s >>= 1) {
        if (threadIdx.x < s) red[threadIdx.x] = fmaxf(red[threadIdx.x], red[threadIdx.x + s]);
        __syncthreads();
    }
    if (threadIdx.x == 0) magmax[blockIdx.x] = red[0];
}

// =====================================================================
// NMS: division-free compares on RAW mag in LDS; 4 px/lane, uchar4
// bucket loads, nibble-LDS word assembly -> Mb (tile-major bitmask).
// Exactness as round 7 (monotone RN(.)/M + 1.0000005f gap + rare exact
// divide fallback under wave-uniform __any).
// =====================================================================
__global__ __launch_bounds__(256, 6) void k_nms_b(const float* __restrict__ mag,
                                                  const unsigned char* __restrict__ bucket,
                                                  const float* __restrict__ magmax,
                                                  u64* __restrict__ Mb,
                                                  float* __restrict__ partial) {
#pragma clang fp contract(off)
    __shared__ float sN[34 * 136];
    __shared__ unsigned int nib32[256];
    __shared__ float red[256];

    const int tid = threadIdx.x;
    const int x0 = blockIdx.x * 128;
    const int y0 = blockIdx.y * 32;
    const int b = blockIdx.z;
    const size_t base = (size_t)b * HW;
    const float M = magmax[b];

    for (int idx = tid; idx < 34 * 34; idx += 256) {
        int r = idx / 34, v = idx - r * 34;
        int gy = y0 - 1 + r;
        int gxv = x0 - 4 + v * 4;
        float4 val = make_float4(0.f, 0.f, 0.f, 0.f);
        if (gy >= 0 && gy < H && gxv >= 0 && gxv <= W - 4)
            val = *(const float4*)&mag[base + (size_t)gy * W + gxv];
        *(float4*)&sN[r * 136 + v * 4] = val;
    }
    __syncthreads();

    const int r = tid >> 5;             // row within 8-row slab
    const int cg = (tid & 31) * 4;
    float amax = 0.0f;

    for (int k4 = 0; k4 < 4; ++k4) {
        const int rr = k4 * 8 + r;      // 0..31
        const int y = y0 + rr;
        unsigned int bk4 = *(const unsigned int*)&bucket[base + (size_t)y * W + x0 + cg];
        float4 a4 = *(const float4*)&sN[(rr + 1) * 136 + cg + 4];
        float av[4] = {a4.x, a4.y, a4.z, a4.w};
        bool im[4];
        bool bad = false;
        float bpv[4], bnv[4];
        bool g1v[4], g2v[4], f1v[4], f2v[4];
#pragma unroll
        for (int j = 0; j < 4; ++j) {
            int c = cg + j;
            int bkt = (bk4 >> (8 * j)) & 0xff;
            int dy = NBDY[bkt], dx = NBDX[bkt];
            float a = av[j];
            float bp = sN[(rr + 1 + dy) * 136 + c + 4 + dx];
            float bn = sN[(rr + 1 - dy) * 136 + c + 4 - dx];
            bpv[j] = bp; bnv[j] = bn;
            bool g1 = a > bp, g2 = a > bn;
            bool f1 = a >= bp * 1.0000005f;
            bool f2 = a >= bn * 1.0000005f;
            g1v[j] = g1; g2v[j] = g2; f1v[j] = f1; f2v[j] = f2;
            im[j] = g1 && g2;
            bad = bad || (g1 && !f1) || (g2 && !f2);
        }
        if (__any(bad)) {
#pragma unroll
            for (int j = 0; j < 4; ++j) {
                bool b1 = g1v[j] && !f1v[j];
                bool b2 = g2v[j] && !f2v[j];
                if (b1 || b2) {
                    float qa = av[j] / M;
                    bool r1 = g1v[j], r2 = g2v[j];
                    if (b1) r1 = qa > (bpv[j] / M);
                    if (b2) r2 = qa > (bnv[j] / M);
                    im[j] = r1 && r2;
                }
            }
        }
        unsigned int nib = 0;
#pragma unroll
        for (int j = 0; j < 4; ++j) {
            if (im[j]) { nib |= 1u << j; amax = fmaxf(amax, av[j]); }
        }
        nib32[tid] = nib;
        __syncthreads();
        if (tid < 16) {
            int rw = tid >> 1, h = tid & 1;
            u64 w = 0;
#pragma unroll
            for (int j = 0; j < 16; ++j)
                w |= (u64)nib32[rw * 32 + h * 16 + j] << (4 * j);
            int yy = y0 + k4 * 8 + rw;
            int widx = ((b << 8) | ((yy >> 6) << 4) | ((x0 >> 6) + h)) * 64 + (yy & 63);
            Mb[widx] = w;
        }
        __syncthreads();
    }

    red[tid] = amax;
    __syncthreads();
    for (int s = 128; s > 0; s >>= 1) {
        if (tid < s) red[tid] = fmaxf(red[tid], red[tid + s]);
        __syncthreads();
    }
    // max(thin) over block = RN(max_surviving_a / M): RN monotone => exact
    if (tid == 0)
        partial[(blockIdx.z * 32 + blockIdx.y) * 8 + blockIdx.x] = red[0] / M;
}

// ---------------- global thin-max + per-image threshold bisection ----------------
__global__ __launch_bounds__(1024) void k_finalize_thr(const float* __restrict__ partial,
                                                       float* __restrict__ hdr,
                                                       float* __restrict__ thr) {
    __shared__ float red[1024];
    float m = 0.0f;
    for (int k = threadIdx.x; k < 4096; k += 1024) m = fmaxf(m, partial[k]);
    red[threadIdx.x] = m;
    __syncthreads();
    for (int s = 512; s > 0; s >>= 1) {
        if (threadIdx.x < s) red[threadIdx.x] = fmaxf(red[threadIdx.x], red[threadIdx.x + s]);
        __syncthreads();
    }
    if (threadIdx.x == 0) hdr[16] = red[0];
    if (threadIdx.x < 32) {
        float tm = red[0];
        int t = threadIdx.x;
        float M = hdr[t >> 1];
        float T = (t & 1) ? (tm * 0.15f) : 0.00392f;
        if (0.0f / M >= T) { thr[t] = 0.0f; return; }
        unsigned int lo = 0u, hi = 0x7f800000u;
        while (hi - lo > 1u) {
            unsigned int mid = lo + ((hi - lo) >> 1);
            if (__uint_as_float(mid) / M >= T) hi = mid; else lo = mid;
        }
        thr[t] = __uint_as_float(hi);
    }
}

// ---------------- threshold: mag + is_max bits -> Sb/Wb (no division) ----------------
__global__ __launch_bounds__(256, 8) void k_thresh_b(const float* __restrict__ mag,
                                                     const u64* __restrict__ Mb,
                                                     const float* __restrict__ hdr,
                                                     const float* __restrict__ thr,
                                                     u64* __restrict__ Sb,
                                                     u64* __restrict__ Wb) {
    __shared__ unsigned int nibS[256], nibW[256];
    const int tid = threadIdx.x;
    const int x0 = blockIdx.x * 128;
    const int y0 = blockIdx.y * 32;
    const int b = blockIdx.z;
    const size_t base = (size_t)b * HW;
    const float Alo = thr[b * 2], Ahi = thr[b * 2 + 1];
    const bool snm = (hdr[16] * 0.15f <= 0.0f);
    const int r = tid >> 5;
    const int cg = (tid & 31) * 4;
    const int hl = cg >> 6;

    for (int k4 = 0; k4 < 4; ++k4) {
        const int rr = k4 * 8 + r;
        const int y = y0 + rr;
        float4 a4 = *(const float4*)&mag[base + (size_t)y * W + x0 + cg];
        float av[4] = {a4.x, a4.y, a4.z, a4.w};
        const int widx = ((b << 8) | ((y >> 6) << 4) | ((x0 >> 6) + hl)) * 64 + (y & 63);
        u64 mw = Mb[widx];
        unsigned int ns = 0, nw = 0;
#pragma unroll
        for (int j = 0; j < 4; ++j) {
            bool im = (mw >> ((cg & 63) + j)) & 1ull;
            bool strong = snm || (im && (av[j] >= Ahi));
            bool weak = (!strong) && im && (av[j] >= Alo);
            ns |= (strong ? 1u : 0u) << j;
            nw |= (weak ? 1u : 0u) << j;
        }
        nibS[tid] = ns;
        nibW[tid] = nw;
        __syncthreads();
        if (tid < 32) {
            bool isW = (tid >= 16);
            int t = tid & 15;
            int rw = t >> 1, h = t & 1;
            const unsigned int* nb = isW ? nibW : nibS;
            u64 w = 0;
#pragma unroll
            for (int j = 0; j < 16; ++j)
                w |= (u64)nb[rw * 32 + h * 16 + j] << (4 * j);
            int yy = y0 + k4 * 8 + rw;
            int widx2 = ((b << 8) | ((yy >> 6) << 4) | ((x0 >> 6) + h)) * 64 + (yy & 63);
            if (isW) Wb[widx2] = w; else Sb[widx2] = w;
        }
        __syncthreads();
    }
}

// ---------------- hysteresis: bit-parallel 64x64 tile per wave, tile-major ----------------
// LAST pass writes the 255/0 float output via shfl row-transpose (coalesced).
template <bool LAST>
__global__ __launch_bounds__(256) void k_hyster_bits(const u64* __restrict__ Wb,
                                                     u64* __restrict__ Sb,
                                                     float* __restrict__ out) {
    const int lane = threadIdx.x & 63;
    const int t = blockIdx.x * 4 + (threadIdx.x >> 6);  // tile id = b*256+ty*16+tx
    const int ty = (t >> 4) & 15;
    const int tx = t & 15;
    const int idx = t * 64 + lane;

    u64 S = Sb[idx];
    const u64 Wk = Wb[idx];

    u64 hstat = 0;
    if (tx > 0)  hstat |= (Sb[(t - 1) * 64 + lane] >> 63) & 1ull;
    if (tx < 15) hstat |= (Sb[(t + 1) * 64 + lane] & 1ull) << 63;

    u64 halo = 0;
    if (lane == 0 && ty > 0) {
        const int ta = t - 16;
        u64 tc = Sb[ta * 64 + 63];
        u64 hh = (tc << 1) | tc | (tc >> 1);
        if (tx > 0)  hh |= (Sb[(ta - 1) * 64 + 63] >> 63) & 1ull;
        if (tx < 15) hh |= (Sb[(ta + 1) * 64 + 63] & 1ull) << 63;
        halo = hh;
    }
    if (lane == 63 && ty < 15) {
        const int tb = t + 16;
        u64 tc = Sb[tb * 64 + 0];
        u64 hh = (tc << 1) | tc | (tc >> 1);
        if (tx > 0)  hh |= (Sb[(tb - 1) * 64 + 0] >> 63) & 1ull;
        if (tx < 15) hh |= (Sb[(tb + 1) * 64 + 0] & 1ull) << 63;
        halo = hh;
    }

    for (int it = 0; it < 160; ++it) {
        u64 hh = (S << 1) | S | (S >> 1) | hstat;
        u64 up = __shfl_up(hh, 1, 64);
        if (lane == 0) up = halo;
        u64 dn = __shfl_down(hh, 1, 64);
        if (lane == 63) dn = halo;
        u64 dil = hh | up | dn;
        u64 nS = S | (Wk & dil);
        bool ch = (nS != S);
        S = nS;
        if (!__any(ch)) break;
    }

    if (!LAST) {
        Sb[idx] = S;
    } else {
        const int bimg = t >> 8;
        float* op = out + (size_t)bimg * HW + (size_t)(ty * 64) * W + tx * 64 + lane;
#pragma unroll 4
        for (int rr = 0; rr < 64; ++rr) {
            u64 wrow = __shfl(S, rr, 64);
            op[(size_t)rr * W] = ((wrow >> lane) & 1ull) ? 255.0f : 0.0f;
        }
    }
}

extern "C" void kernel_launch(void* const* d_in, const int* in_sizes, int n_in,
                              void* d_out, int out_size, void* d_ws, size_t ws_size,
                              hipStream_t stream) {
    (void)in_sizes; (void)n_in; (void)out_size; (void)ws_size;
    const float* img = (const float*)d_in[0];
    float* out = (float*)d_out;

    // workspace layout
    float* hdr = (float*)d_ws;                 // [0..15]=magmax, [16]=thinmax
    float* thr = hdr + 64;                     // 32 floats: per-image Alo/Ahi
    float* partialA = hdr + 128;               // 16384 floats (K1 blocks)
    float* partialB = partialA + 16384;        // 4096 floats (nms blocks)
    float* A = partialB + 4096;                // mag, 64 MB (16B-aligned)
    unsigned char* C = (unsigned char*)(A + (size_t)NTOT);  // bucket, 16 MB
    u64* Sb = (u64*)(C + (size_t)NTOT);        // strong bits, 2 MB
    u64* Wb = Sb + NTOT / 64;                  // weak bits, 2 MB
    u64* Mb = Wb + NTOT / 64;                  // is_max bits, 2 MB

    dim3 blk(256);
    k_smooth_sobel<<<dim3(8, 128, BB), blk, 0, stream>>>(img, A, C, partialA);
    k_redmax_img<<<dim3(BB), blk, 0, stream>>>(partialA, hdr);
    k_nms_b<<<dim3(8, 32, BB), blk, 0, stream>>>(A, C, hdr, Mb, partialB);
    k_finalize_thr<<<dim3(1), dim3(1024), 0, stream>>>(partialB, hdr, thr);
    k_thresh_b<<<dim3(8, 32, BB), blk, 0, stream>>>(A, Mb, hdr, thr, Sb, Wb);
    for (int p = 0; p < 5; ++p)
        k_hyster_bits<false><<<dim3(NTOT / (64 * 64) / 4), blk, 0, stream>>>(Wb, Sb, out);
    k_hyster_bits<true><<<dim3(NTOT / (64 * 64) / 4), blk, 0, stream>>>(Wb, Sb, out);
}